// Round 7
// baseline (120.712 us; speedup 1.0000x reference)
//
#include <hip/hip_runtime.h>
#include <hip/hip_bf16.h>
#include <math.h>

// Problem constants (B,S,R,A,DW,DR) = (64,32,128,64,512,512)
#define B_  64
#define S_  32
#define R_  128
#define A_  64
#define DW_ 512
#define DR_ 512

typedef __attribute__((ext_vector_type(8))) short short8;   // 8 bf16 (4 VGPRs)
typedef __attribute__((ext_vector_type(4))) float f32x4;    // MFMA accumulator

__device__ __forceinline__ unsigned short bf16_rn(float x) {
    union { float f; unsigned u; } v; v.f = x;
    unsigned r = v.u + 0x7FFF + ((v.u >> 16) & 1);
    return (unsigned short)(r >> 16);
}
__device__ __forceinline__ float bf16_to_f(unsigned short h) {
    union { unsigned u; float f; } v; v.u = ((unsigned)h) << 16;
    return v.f;
}

// Swizzled LDS index for a [64][32] bf16 tile (4 chunks of 8 bf16 per row).
__device__ __forceinline__ int swz(int row, int chunk) {
    return row * 32 + ((chunk ^ ((row >> 1) & 3)) << 3);
}

// C[M,N] = A[M,K] @ Bm[N,K]^T + bias1[N] (+ bias2[N]) (+ rowv[m]*colv[n])
// Split-bf16 MFMA (validated r5/r6: absmax 0.00195). This round: double-
// buffered LDS -> ONE barrier per K-step (was two), next-step global loads
// issued a full frag-read+MFMA phase before their use (convert+write).
__global__ __launch_bounds__(256) void gemm_dual_kernel(
    const float* __restrict__ A0, const float* __restrict__ B0, float* __restrict__ C0,
    int M0, int N0, int K0,
    const float* __restrict__ bias1_0, const float* __restrict__ bias2_0,
    const float* __restrict__ rowv0, const float* __restrict__ colv0,
    const float* __restrict__ A1, const float* __restrict__ B1, float* __restrict__ C1,
    int M1, int N1, int K1,
    const float* __restrict__ bias1_1)
{
    const int z = blockIdx.z;
    const float* Am; const float* Bm; float* C;
    const float *bias1, *bias2, *rowv, *colv;
    int M, N, K;
    if (z == 0) {
        Am = A0; Bm = B0; C = C0; M = M0; N = N0; K = K0;
        bias1 = bias1_0; bias2 = bias2_0; rowv = rowv0; colv = colv0;
    } else {
        Am = A1; Bm = B1; C = C1; M = M1; N = N1; K = K1;
        bias1 = bias1_1; bias2 = nullptr; rowv = nullptr; colv = nullptr;
    }

    const int bm = blockIdx.x * 64;
    const int bn = blockIdx.y * 64;
    if (bm >= M || bn >= N) return;

    __shared__ unsigned short Ahi[2][64 * 32], Alo[2][64 * 32];
    __shared__ unsigned short Bhi[2][64 * 32], Blo[2][64 * 32];

    const int tid  = threadIdx.x;
    const int l    = tid & 63;
    const int w    = tid >> 6;
    const int wr   = w >> 1;
    const int wc   = w & 1;
    const int fr   = l & 15;
    const int fc   = l >> 4;
    const int srow = tid >> 2;
    const int sch  = tid & 3;

    f32x4 acc[2][2] = {};

    float4 ra0, ra1, rb0, rb1;

    // prologue: load step 0, convert, write buf 0
    {
        const size_t arow = (size_t)(bm + srow) * K + sch * 8;
        const size_t brow = (size_t)(bn + srow) * K + sch * 8;
        ra0 = *(const float4*)&Am[arow];     ra1 = *(const float4*)&Am[arow + 4];
        rb0 = *(const float4*)&Bm[brow];     rb1 = *(const float4*)&Bm[brow + 4];

        short8 ahi, alo, bhi, blo;
        float af[8] = {ra0.x, ra0.y, ra0.z, ra0.w, ra1.x, ra1.y, ra1.z, ra1.w};
        float bf[8] = {rb0.x, rb0.y, rb0.z, rb0.w, rb1.x, rb1.y, rb1.z, rb1.w};
        #pragma unroll
        for (int e = 0; e < 8; ++e) {
            unsigned short h = bf16_rn(af[e]);
            ahi[e] = (short)h;
            alo[e] = (short)bf16_rn(af[e] - bf16_to_f(h));
            unsigned short g = bf16_rn(bf[e]);
            bhi[e] = (short)g;
            blo[e] = (short)bf16_rn(bf[e] - bf16_to_f(g));
        }
        *(short8*)&Ahi[0][swz(srow, sch)] = ahi;
        *(short8*)&Alo[0][swz(srow, sch)] = alo;
        *(short8*)&Bhi[0][swz(srow, sch)] = bhi;
        *(short8*)&Blo[0][swz(srow, sch)] = blo;
    }
    __syncthreads();

    const int nsteps = K >> 5;
    int cur = 0;
    for (int s = 0; s < nsteps; ++s) {
        // issue next-step global loads first (hide under frag reads + MFMA)
        if (s + 1 < nsteps) {
            const int k0 = (s + 1) << 5;
            const size_t arow = (size_t)(bm + srow) * K + k0 + sch * 8;
            const size_t brow = (size_t)(bn + srow) * K + k0 + sch * 8;
            ra0 = *(const float4*)&Am[arow];     ra1 = *(const float4*)&Am[arow + 4];
            rb0 = *(const float4*)&Bm[brow];     rb1 = *(const float4*)&Bm[brow + 4];
        }

        // frag reads from buf[cur] + 12 MFMA
        short8 fahi[2], falo[2], fbhi[2], fblo[2];
        #pragma unroll
        for (int i = 0; i < 2; ++i) {
            const int r = wr * 32 + i * 16 + fr;
            fahi[i] = *(const short8*)&Ahi[cur][swz(r, fc)];
            falo[i] = *(const short8*)&Alo[cur][swz(r, fc)];
            const int c = wc * 32 + i * 16 + fr;
            fbhi[i] = *(const short8*)&Bhi[cur][swz(c, fc)];
            fblo[i] = *(const short8*)&Blo[cur][swz(c, fc)];
        }
        #pragma unroll
        for (int i = 0; i < 2; ++i)
            #pragma unroll
            for (int j = 0; j < 2; ++j) {
                acc[i][j] = __builtin_amdgcn_mfma_f32_16x16x32_bf16(fahi[i], fbhi[j], acc[i][j], 0, 0, 0);
                acc[i][j] = __builtin_amdgcn_mfma_f32_16x16x32_bf16(fahi[i], fblo[j], acc[i][j], 0, 0, 0);
                acc[i][j] = __builtin_amdgcn_mfma_f32_16x16x32_bf16(falo[i], fbhi[j], acc[i][j], 0, 0, 0);
            }

        // convert next-step regs and write the OTHER buffer; one barrier/step.
        // (step s+1's reads of buf[cur^1] are after this barrier; step s's
        // reads of buf[cur] are before it -> no read/write hazard.)
        if (s + 1 < nsteps) {
            short8 ahi, alo, bhi, blo;
            float af[8] = {ra0.x, ra0.y, ra0.z, ra0.w, ra1.x, ra1.y, ra1.z, ra1.w};
            float bf[8] = {rb0.x, rb0.y, rb0.z, rb0.w, rb1.x, rb1.y, rb1.z, rb1.w};
            #pragma unroll
            for (int e = 0; e < 8; ++e) {
                unsigned short h = bf16_rn(af[e]);
                ahi[e] = (short)h;
                alo[e] = (short)bf16_rn(af[e] - bf16_to_f(h));
                unsigned short g = bf16_rn(bf[e]);
                bhi[e] = (short)g;
                blo[e] = (short)bf16_rn(bf[e] - bf16_to_f(g));
            }
            const int nxt = cur ^ 1;
            *(short8*)&Ahi[nxt][swz(srow, sch)] = ahi;
            *(short8*)&Alo[nxt][swz(srow, sch)] = alo;
            *(short8*)&Bhi[nxt][swz(srow, sch)] = bhi;
            *(short8*)&Blo[nxt][swz(srow, sch)] = blo;
            __syncthreads();
            cur = nxt;
        }
    }

    // Epilogue. C/D layout (m89): col = l&15, row = (l>>4)*4 + reg.
    #pragma unroll
    for (int i = 0; i < 2; ++i)
        #pragma unroll
        for (int j = 0; j < 2; ++j) {
            const int n  = bn + wc * 32 + j * 16 + fr;
            const float b1 = bias1[n];
            const float b2 = bias2 ? bias2[n] : 0.0f;
            const float cv = colv ? colv[n] : 0.0f;
            #pragma unroll
            for (int reg = 0; reg < 4; ++reg) {
                const int m = bm + wr * 32 + i * 16 + fc * 4 + reg;
                float v = acc[i][j][reg] + b1 + b2;
                if (rowv) v += rowv[m] * cv;
                C[(size_t)m * N + n] = v;
            }
        }
}

// One block per (b, group of 8 a's). Folded-tanh identity:
//   sum_d wa_d*tanh(u_d+rp_d) = sum_d wa_d - 2*sum_d wa_d/(exp2(K2*u_d+rp2_d)+1)
// 3 VALU + 2 TRANS per element, no clamp needed. u/qv rows loaded once and
// reused across 8 a's (halves L2 traffic vs G=4); 512 blocks = 2/CU.
__global__ __launch_bounds__(256) void attn_kernel(
    const float* __restrict__ u,      // [B*S, DR]
    const float* __restrict__ rp,     // [R, DR]
    const float* __restrict__ watt,   // [DR]
    const float* __restrict__ battp,  // [1]
    const float* __restrict__ qv,     // [B*S, DW]
    const unsigned char* __restrict__ mask, // [B*S]
    const int* __restrict__ rspace,   // [B*A]
    float* __restrict__ out,          // [B*A, DW]
    float* __restrict__ alpha_out)    // [B*A, S]
{
    const int blk  = blockIdx.x;      // b*8 + grp
    const int b    = blk >> 3;
    const int ba0  = b * A_ + ((blk & 7) << 3);  // first of 8 consecutive a's
    const int tid  = threadIdx.x;
    const int lane = tid & 63;
    const int wave = tid >> 6;

    const float K2 = 2.8853900817779268f;  // 2*log2(e)

    __shared__ float s_scores[8][S_];
    __shared__ float s_alpha[8][S_];

    // Stage Watt and the 8 rp rows (pre-scaled by K2) into registers.
    float wav[8], rp2[8][8];
    {
        const float4* wa4 = (const float4*)watt;
        #pragma unroll
        for (int v = 0; v < 2; ++v) {
            float4 w = wa4[v * 64 + lane];
            wav[v*4+0] = w.x; wav[v*4+1] = w.y; wav[v*4+2] = w.z; wav[v*4+3] = w.w;
        }
        #pragma unroll
        for (int g = 0; g < 8; ++g) {
            const float4* rp4 = (const float4*)(rp + (size_t)rspace[ba0 + g] * DR_);
            #pragma unroll
            for (int v = 0; v < 2; ++v) {
                float4 t = rp4[v * 64 + lane];
                rp2[g][v*4+0] = t.x * K2; rp2[g][v*4+1] = t.y * K2;
                rp2[g][v*4+2] = t.z * K2; rp2[g][v*4+3] = t.w * K2;
            }
        }
    }
    const float batt = battp[0];

    // swa = sum_d wa_d (wave-reduced once)
    float swa = wav[0] + wav[1] + wav[2] + wav[3] + wav[4] + wav[5] + wav[6] + wav[7];
    #pragma unroll
    for (int off = 32; off > 0; off >>= 1)
        swa += __shfl_xor(swa, off);

    // Scores: wave w handles s = w*8 .. w*8+7 for all 8 a's.
    #pragma unroll
    for (int si = 0; si < 8; ++si) {
        const int s = (wave << 3) + si;
        const float4* u4 = (const float4*)(u + ((size_t)b * S_ + s) * DR_);
        float uu[8];
        #pragma unroll
        for (int v = 0; v < 2; ++v) {
            float4 t = u4[v * 64 + lane];
            uu[v*4+0] = t.x; uu[v*4+1] = t.y; uu[v*4+2] = t.z; uu[v*4+3] = t.w;
        }
        float ac[8] = {};
        #pragma unroll
        for (int e = 0; e < 8; ++e) {
            const float ue = uu[e];
            const float we = wav[e];
            const float uk = ue * K2;
            #pragma unroll
            for (int g = 0; g < 8; ++g) {
                float zz = __builtin_amdgcn_exp2f(uk + rp2[g][e]);
                ac[g] = fmaf(we, __builtin_amdgcn_rcpf(zz + 1.0f), ac[g]);
            }
        }
        #pragma unroll
        for (int off = 32; off > 0; off >>= 1)
            #pragma unroll
            for (int g = 0; g < 8; ++g)
                ac[g] += __shfl_xor(ac[g], off);
        if (lane == 0)
            #pragma unroll
            for (int g = 0; g < 8; ++g)
                s_scores[g][s] = fmaf(-2.0f, ac[g], swa) + batt;
    }
    __syncthreads();

    // Softmax: one 32-lane group per a (8 groups over all 256 threads).
    {
        const int g = tid >> 5;
        const int s = tid & 31;
        float sc = s_scores[g][s];
        if (mask[b * S_ + s]) sc = -INFINITY;
        float m = sc;
        #pragma unroll
        for (int off = 16; off > 0; off >>= 1)
            m = fmaxf(m, __shfl_xor(m, off));
        float e = __expf(sc - m);
        float sum = e;
        #pragma unroll
        for (int off = 16; off > 0; off >>= 1)
            sum += __shfl_xor(sum, off);
        float al = e / sum;
        s_alpha[g][s] = al;
        alpha_out[(size_t)(ba0 + g) * S_ + s] = al;
    }
    __syncthreads();

    // ctx: qv rows shared across the 8 a's. Thread owns w = tid*2, tid*2+1.
    float2 acc2[8] = {};
    const float* qb = qv + (size_t)b * S_ * DW_;
    #pragma unroll 4
    for (int s = 0; s < S_; ++s) {
        float2 q = *(const float2*)&qb[s * DW_ + tid * 2];
        #pragma unroll
        for (int g = 0; g < 8; ++g) {
            const float al = s_alpha[g][s];
            acc2[g].x = fmaf(al, q.x, acc2[g].x);
            acc2[g].y = fmaf(al, q.y, acc2[g].y);
        }
    }
    #pragma unroll
    for (int g = 0; g < 8; ++g)
        *(float2*)&out[(size_t)(ba0 + g) * DW_ + tid * 2] = acc2[g];
}

extern "C" void kernel_launch(void* const* d_in, const int* in_sizes, int n_in,
                              void* d_out, int out_size, void* d_ws, size_t ws_size,
                              hipStream_t stream) {
    const float*         qv   = (const float*)d_in[0];          // [B,S,DW]
    const unsigned char* mask = (const unsigned char*)d_in[1];  // [B,S] bool
    const int*           rsp  = (const int*)d_in[2];            // [B,A]
    const float*         cov  = (const float*)d_in[3];          // [B,S]
    const float*         rel  = (const float*)d_in[4];          // [R,DR]
    const float*         Wq   = (const float*)d_in[5];          // [DR,DW]
    const float*         bq   = (const float*)d_in[6];          // [DR]
    const float*         Wr   = (const float*)d_in[7];          // [DR,DR]
    const float*         br   = (const float*)d_in[8];          // [DR]
    const float*         Wc   = (const float*)d_in[9];          // [DR,1] -> [DR]
    const float*         bc   = (const float*)d_in[10];         // [DR]
    const float*         Watt = (const float*)d_in[11];         // [1,DR] -> [DR]
    const float*         batt = (const float*)d_in[12];         // [1]

    // Workspace: u [B*S,DR] = 4 MB, rp [R,DR] = 256 KB
    float* u  = (float*)d_ws;
    float* rp = u + (size_t)B_ * S_ * DR_;

    float* out       = (float*)d_out;                 // [B,A,DW]
    float* alpha_out = out + (size_t)B_ * A_ * DW_;   // [B,A,S]

    dim3 blk(256);

    gemm_dual_kernel<<<dim3((B_ * S_) / 64, DR_ / 64, 2), blk, 0, stream>>>(
        qv, Wq, u, B_ * S_, DR_, DW_, bq, bc, cov, Wc,
        rel, Wr, rp, R_, DR_, DR_, br);

    attn_kernel<<<dim3(B_ * (A_ / 8)), blk, 0, stream>>>(
        u, rp, Watt, batt, qv, mask, rsp, out, alpha_out);
}